// Round 4
// baseline (184.511 us; speedup 1.0000x reference)
//
#include <hip/hip_runtime.h>

// AntModel: counts through 3 routing layers == one composed routing table.
//   out[b, dest3[dest2[dest1[s]]]] += x[b, s]; dest_k[s] = argmax_j Wk[s,j].
//
// R3 -> R4: argmax was stuck at 2.8 TB/s effective, invariant to HBM-vs-L3
// and to per-wave MLP. Theory: 16KB-strided instantaneous footprint defeats
// the channel/XCD interleave. Fix: per-wave chunk phase swizzle (dense
// instantaneous footprint), single-round balanced grid (2048 blocks, one big
// row + half a W3 row per wave, W3 combined via packed u64 atomicMax), and
// compose fused into the scatter kernel.

#define N_IN   4096
#define N_MID  4096
#define N_OUT  1024
#define BATCH  256

using u32 = unsigned int;
using u64 = unsigned long long;

// order-preserving float->u32 (monotone: a<b  <=>  forder(a)<forder(b))
__device__ __forceinline__ u32 forder(float f) {
    u32 b = __float_as_uint(f);
    return (b & 0x80000000u) ? ~b : (b | 0x80000000u);
}

// exact first-max (jnp.argmax): value desc, index asc
__device__ __forceinline__ void upd(float v, int idx, float& bv, int& bi) {
    if (v > bv || (v == bv && idx < bi)) { bv = v; bi = idx; }
}

__device__ __forceinline__ void wave_reduce(float& bv, int& bi) {
    #pragma unroll
    for (int off = 1; off < 64; off <<= 1) {
        float ov = __shfl_xor(bv, off, 64);
        int   oi = __shfl_xor(bi, off, 64);
        if (ov > bv || (ov == bv && oi < bi)) { bv = ov; bi = oi; }
    }
}

__global__ __launch_bounds__(256) void argmax_fused_kernel(
    const float* __restrict__ W1, const float* __restrict__ W2,
    const float* __restrict__ W3, int* __restrict__ dest1,
    int* __restrict__ dest2, u64* __restrict__ packed3) {
    const int g    = (blockIdx.x * 256 + (int)threadIdx.x) >> 6;  // 0..8191
    const int lane = threadIdx.x & 63;

    // ---- big row: W1 row g (g<4096) else W2 row g-4096; 16 chunks of 1KB ----
    const int rowB = g & (N_IN - 1);
    const float4* __restrict__ pb = reinterpret_cast<const float4*>(
        ((g < N_IN) ? W1 : W2) + (size_t)rowB * N_MID);
    const int phase = g & 15;

    // ---- W3 half-row: row g>>1, chunks {2h, 2h+1}, h = g&1 (2KB, contiguous
    //      across consecutive waves: base address == g*2KB) ----
    const int row3  = g >> 1;
    const int cbase = (g & 1) * 2;
    const float4* __restrict__ p3 =
        reinterpret_cast<const float4*>(W3 + (size_t)row3 * N_OUT);

    // batch A: 8 swizzled chunks + both W3 chunks in flight (10KB/wave)
    float4 va[8];
    int ca[8];
    #pragma unroll
    for (int j = 0; j < 8; ++j) {
        ca[j] = (j + phase) & 15;
        va[j] = pb[ca[j] * 64 + lane];
    }
    float4 v3[2];
    v3[0] = p3[(cbase + 0) * 64 + lane];
    v3[1] = p3[(cbase + 1) * 64 + lane];

    float bv = -__builtin_huge_valf(); int bi = 0;
    #pragma unroll
    for (int j = 0; j < 8; ++j) {
        const int c = ca[j] * 256 + lane * 4;
        upd(va[j].x, c + 0, bv, bi);
        upd(va[j].y, c + 1, bv, bi);
        upd(va[j].z, c + 2, bv, bi);
        upd(va[j].w, c + 3, bv, bi);
    }
    // batch B: remaining 8 chunks
    float4 vb[8];
    int cb[8];
    #pragma unroll
    for (int j = 0; j < 8; ++j) {
        cb[j] = (j + 8 + phase) & 15;
        vb[j] = pb[cb[j] * 64 + lane];
    }
    #pragma unroll
    for (int j = 0; j < 8; ++j) {
        const int c = cb[j] * 256 + lane * 4;
        upd(vb[j].x, c + 0, bv, bi);
        upd(vb[j].y, c + 1, bv, bi);
        upd(vb[j].z, c + 2, bv, bi);
        upd(vb[j].w, c + 3, bv, bi);
    }
    wave_reduce(bv, bi);
    if (lane == 0) ((g < N_IN) ? dest1 : dest2)[rowB] = bi;

    // ---- W3 half-row reduce + cross-wave combine ----
    float b3 = -__builtin_huge_valf(); int i3 = 0;
    #pragma unroll
    for (int t = 0; t < 2; ++t) {
        const int c = (cbase + t) * 256 + lane * 4;
        upd(v3[t].x, c + 0, b3, i3);
        upd(v3[t].y, c + 1, b3, i3);
        upd(v3[t].z, c + 2, b3, i3);
        upd(v3[t].w, c + 3, b3, i3);
    }
    wave_reduce(b3, i3);
    if (lane == 0) {
        // key: (monotone value, ~idx) -> max key == (max value, min idx)
        u64 key = ((u64)forder(b3) << 32) | (u32)(~(u32)i3);
        atomicMax(&packed3[row3], key);
    }
}

__global__ __launch_bounds__(256) void scatter_fused_kernel(
    const int* __restrict__ x, const int* __restrict__ dest1,
    const int* __restrict__ dest2, const u64* __restrict__ packed3,
    float* __restrict__ out) {
    __shared__ int fd[N_IN];
    __shared__ int cnt[N_OUT];
    const int b = blockIdx.x;
    // compose routing chain (redundant per block; dest tables are L2-hot)
    for (int s = threadIdx.x; s < N_IN; s += 256) {
        int d1 = dest1[s];
        int d2 = dest2[d1];
        u64 p  = packed3[d2];
        fd[s]  = (int)(~(u32)p);
    }
    for (int i = threadIdx.x; i < N_OUT; i += 256) cnt[i] = 0;
    __syncthreads();
    const int4* __restrict__ x4 =
        reinterpret_cast<const int4*>(x + (size_t)b * N_IN);
    for (int q = threadIdx.x; q < N_IN / 4; q += 256) {
        int4 v = x4[q];
        int s = q * 4;
        atomicAdd(&cnt[fd[s + 0]], v.x);
        atomicAdd(&cnt[fd[s + 1]], v.y);
        atomicAdd(&cnt[fd[s + 2]], v.z);
        atomicAdd(&cnt[fd[s + 3]], v.w);
    }
    __syncthreads();
    float* __restrict__ ob = out + (size_t)b * N_OUT;
    for (int i = threadIdx.x; i < N_OUT; i += 256) ob[i] = (float)cnt[i];
}

extern "C" void kernel_launch(void* const* d_in, const int* in_sizes, int n_in,
                              void* d_out, int out_size, void* d_ws, size_t ws_size,
                              hipStream_t stream) {
    const int*   x  = (const int*)d_in[0];
    const float* W1 = (const float*)d_in[1];
    const float* W2 = (const float*)d_in[2];
    const float* W3 = (const float*)d_in[3];
    float* out = (float*)d_out;

    u64* packed3 = (u64*)d_ws;                 // [4096] u64 (W3 rows)
    int* dest1   = (int*)(packed3 + N_MID);    // [4096]
    int* dest2   = dest1 + N_IN;               // [4096]

    hipMemsetAsync(packed3, 0, N_MID * sizeof(u64), stream);
    argmax_fused_kernel<<<(N_IN + N_MID) / 4, 256, 0, stream>>>(
        W1, W2, W3, dest1, dest2, packed3);
    scatter_fused_kernel<<<BATCH, 256, 0, stream>>>(x, dest1, dest2, packed3,
                                                    out);
}

// Round 5
// 170.836 us; speedup vs baseline: 1.0801x; 1.0801x over previous
//
#include <hip/hip_runtime.h>

// AntModel == composed routing: out[b, dest3[dest2[dest1[s]]]] += x[b,s],
// dest_k[s] = argmax_j Wk[s,j] (first max).
//
// R4 -> R5: argmax invariant at ~55us across 3 access patterns; read path
// delivers ~2.7 TB/s (all reads are L2 misses; fill ceiling ~3.1 TB/s from
// m13 copy = 6.29/2 per direction). Last lever: max miss-level parallelism.
// Contiguous 8KB half-row per wave (20480 waves, zero LDS, VGPR<=48, full
// occupancy), halves combined via packed (forder(v), ~idx) u64 atomicMax.
// If this doesn't move, ~2.7 TB/s is the pattern-independent floor.

#define N_IN   4096
#define N_MID  4096
#define N_OUT  1024
#define BATCH  256

using u32 = unsigned int;
using u64 = unsigned long long;

// order-preserving float->u32: a<b <=> forder(a)<forder(b); always > 0
__device__ __forceinline__ u32 forder(float f) {
    u32 b = __float_as_uint(f);
    return (b & 0x80000000u) ? ~b : (b | 0x80000000u);
}

__device__ __forceinline__ void upd(float v, int idx, float& bv, int& bi) {
    if (v > bv) { bv = v; bi = idx; }   // per-lane idx strictly increases
}

__device__ __forceinline__ void wave_reduce(float& bv, int& bi) {
    #pragma unroll
    for (int off = 1; off < 64; off <<= 1) {
        float ov = __shfl_xor(bv, off, 64);
        int   oi = __shfl_xor(bi, off, 64);
        if (ov > bv || (ov == bv && oi < bi)) { bv = ov; bi = oi; }
    }
}

__global__ __launch_bounds__(256) void argmax_kernel(
    const float* __restrict__ W1, const float* __restrict__ W2,
    const float* __restrict__ W3, u64* __restrict__ p1,
    u64* __restrict__ p2, int* __restrict__ dest3) {
    const int g    = (blockIdx.x * 256 + (int)threadIdx.x) >> 6;  // 0..20479
    const int lane = threadIdx.x & 63;

    if (g < 2 * (N_IN + N_MID)) {                 // W1/W2 half-rows (8 KB)
        const bool  isW1 = g < 2 * N_IN;
        const int   idx  = g & (2 * N_IN - 1);
        const int   row  = idx >> 1;
        const int   half = idx & 1;
        const float4* __restrict__ p = reinterpret_cast<const float4*>(
            (isW1 ? W1 : W2) + (size_t)row * N_MID + half * 2048);
        float4 v[8];
        #pragma unroll
        for (int t = 0; t < 8; ++t) v[t] = p[t * 64 + lane];
        float bv = -__builtin_huge_valf(); int bi = 0;
        #pragma unroll
        for (int t = 0; t < 8; ++t) {
            const int c = half * 2048 + t * 256 + lane * 4;
            upd(v[t].x, c + 0, bv, bi);
            upd(v[t].y, c + 1, bv, bi);
            upd(v[t].z, c + 2, bv, bi);
            upd(v[t].w, c + 3, bv, bi);
        }
        wave_reduce(bv, bi);
        if (lane == 0) {
            u64 key = ((u64)forder(bv) << 32) | (u32)(~(u32)bi);
            atomicMax(&(isW1 ? p1 : p2)[row], key);
        }
    } else {                                      // W3 full row (4 KB)
        const int r = g - 2 * (N_IN + N_MID);
        const float4* __restrict__ p =
            reinterpret_cast<const float4*>(W3 + (size_t)r * N_OUT);
        float4 v[4];
        #pragma unroll
        for (int t = 0; t < 4; ++t) v[t] = p[t * 64 + lane];
        float bv = -__builtin_huge_valf(); int bi = 0;
        #pragma unroll
        for (int t = 0; t < 4; ++t) {
            const int c = t * 256 + lane * 4;
            upd(v[t].x, c + 0, bv, bi);
            upd(v[t].y, c + 1, bv, bi);
            upd(v[t].z, c + 2, bv, bi);
            upd(v[t].w, c + 3, bv, bi);
        }
        wave_reduce(bv, bi);
        if (lane == 0) dest3[r] = bi;
    }
}

__global__ __launch_bounds__(256) void compose_kernel(
    const u64* __restrict__ p1, const u64* __restrict__ p2,
    const int* __restrict__ dest3, int* __restrict__ fdest) {
    const int s = blockIdx.x * blockDim.x + threadIdx.x;
    if (s < N_IN) {
        int d1 = (int)(~(u32)p1[s]) & (N_MID - 1);
        int d2 = (int)(~(u32)p2[d1]) & (N_MID - 1);
        fdest[s] = dest3[d2];
    }
}

__global__ __launch_bounds__(256) void scatter_kernel(
    const int* __restrict__ x, const int* __restrict__ fdest,
    float* __restrict__ out) {
    __shared__ int cnt[N_OUT];
    const int b = blockIdx.x;
    for (int i = threadIdx.x; i < N_OUT; i += 256) cnt[i] = 0;
    __syncthreads();
    const int4* __restrict__ x4 =
        reinterpret_cast<const int4*>(x + (size_t)b * N_IN);
    const int4* __restrict__ f4 = reinterpret_cast<const int4*>(fdest);
    for (int q = threadIdx.x; q < N_IN / 4; q += 256) {
        int4 v = x4[q];
        int4 d = f4[q];
        atomicAdd(&cnt[d.x], v.x);
        atomicAdd(&cnt[d.y], v.y);
        atomicAdd(&cnt[d.z], v.z);
        atomicAdd(&cnt[d.w], v.w);
    }
    __syncthreads();
    float* __restrict__ ob = out + (size_t)b * N_OUT;
    for (int i = threadIdx.x; i < N_OUT; i += 256) ob[i] = (float)cnt[i];
}

extern "C" void kernel_launch(void* const* d_in, const int* in_sizes, int n_in,
                              void* d_out, int out_size, void* d_ws, size_t ws_size,
                              hipStream_t stream) {
    const int*   x  = (const int*)d_in[0];
    const float* W1 = (const float*)d_in[1];
    const float* W2 = (const float*)d_in[2];
    const float* W3 = (const float*)d_in[3];
    float* out = (float*)d_out;

    u64* p1    = (u64*)d_ws;               // [4096] u64
    u64* p2    = p1 + N_IN;                // [4096] u64
    int* dest3 = (int*)(p2 + N_MID);       // [4096] int
    int* fdest = dest3 + N_MID;            // [4096] int

    // all true keys have bit63 set (forder > 0) -> memset-0 is a valid floor
    hipMemsetAsync(p1, 0, 2 * N_IN * sizeof(u64), stream);

    const int total_waves = 2 * (N_IN + N_MID) + N_MID;  // 20480
    argmax_kernel<<<total_waves / 4, 256, 0, stream>>>(W1, W2, W3, p1, p2,
                                                       dest3);
    compose_kernel<<<N_IN / 256, 256, 0, stream>>>(p1, p2, dest3, fdest);
    scatter_kernel<<<BATCH, 256, 0, stream>>>(x, fdest, out);
}